// Round 8
// baseline (239.462 us; speedup 1.0000x reference)
//
#include <hip/hip_runtime.h>
#include <hip/hip_bf16.h>
#include <cstdint>

#define C_DIM 1024
#define L_DIM 2048
#define N_DIM 4
#define M_DIM (N_DIM * L_DIM)   // 8192

typedef __attribute__((ext_vector_type(8))) short frag8;    // 8 bf16 = 4 VGPRs
typedef __attribute__((ext_vector_type(4)))  float f32x4;
typedef __attribute__((ext_vector_type(16))) float f32x16;

// ---------------- helpers ----------------
__device__ __forceinline__ void gl_lds16(const void* g, void* l) {
  __builtin_amdgcn_global_load_lds((const __attribute__((address_space(1))) void*)g,
                                   (__attribute__((address_space(3))) void*)l,
                                   16, 0, 0);
}
__device__ __forceinline__ void store_out(float* Y, size_t idx, float v) { Y[idx] = v; }
__device__ __forceinline__ void store_out(__hip_bfloat16* Y, size_t idx, float v) {
  Y[idx] = __float2bfloat16(v);
}
__device__ __forceinline__ float4 ldbf4(const __hip_bfloat16* p) {
  union { short4 s; __hip_bfloat16 h[4]; } u; u.s = *(const short4*)p;
  return make_float4((float)u.h[0], (float)u.h[1], (float)u.h[2], (float)u.h[3]);
}
__device__ __forceinline__ void stbf4(__hip_bfloat16* p, float4 v) {
  union { short4 s; __hip_bfloat16 h[4]; } u;
  u.h[0] = __float2bfloat16(v.x); u.h[1] = __float2bfloat16(v.y);
  u.h[2] = __float2bfloat16(v.z); u.h[3] = __float2bfloat16(v.w);
  *(short4*)p = u.s;
}
struct Ld8f { float4 a, b; };
__device__ __forceinline__ Ld8f ld8(const float* p) {
  return { *(const float4*)p, *(const float4*)(p + 4) };
}
__device__ __forceinline__ void st8(__hip_bfloat16* l, const Ld8f& v) {
  union { __hip_bfloat16 h[8]; int4 q; } u;
  u.h[0] = __float2bfloat16(v.a.x); u.h[1] = __float2bfloat16(v.a.y);
  u.h[2] = __float2bfloat16(v.a.z); u.h[3] = __float2bfloat16(v.a.w);
  u.h[4] = __float2bfloat16(v.b.x); u.h[5] = __float2bfloat16(v.b.y);
  u.h[6] = __float2bfloat16(v.b.z); u.h[7] = __float2bfloat16(v.b.w);
  *(int4*)l = u.q;
}

// ---- single-launch weight conversion: Wi, Wout (1M each), Wo, Wm (7168 each) ----
__global__ __launch_bounds__(256)
void cvt_weights(const float* __restrict__ Wi, const float* __restrict__ Wout,
                 const float* __restrict__ Wo, const float* __restrict__ Wm,
                 __hip_bfloat16* __restrict__ Wib, __hip_bfloat16* __restrict__ Woutb,
                 __hip_bfloat16* __restrict__ Wob, __hip_bfloat16* __restrict__ Wmb)
{
  const int b = blockIdx.x;
  const float* src; __hip_bfloat16* dst; int i; int n8;
  if (b < 512)       { src = Wi;   dst = Wib;   i = b * 256 + threadIdx.x;          n8 = 131072; }
  else if (b < 1024) { src = Wout; dst = Woutb; i = (b - 512) * 256 + threadIdx.x;  n8 = 131072; }
  else if (b < 1028) { src = Wo;   dst = Wob;   i = (b - 1024) * 256 + threadIdx.x; n8 = 896; }
  else               { src = Wm;   dst = Wmb;   i = (b - 1028) * 256 + threadIdx.x; n8 = 896; }
  if (i >= n8) return;
  st8(dst + (size_t)i * 8, ld8(src + (size_t)i * 8));
}

// ------- gemm1 hybrid: A register-staged from fp32 (inline cvt), B bf16 gl_lds -----
// Y[M,N] = X[M,K] @ W[N,K]^T + bias. 128x128 tile, BK=32, 32x32x16 MFMA.
__global__ __launch_bounds__(256, 2)
void gemm_hyb(const float* __restrict__ X,
              const __hip_bfloat16* __restrict__ W,
              const float* __restrict__ bias,
              __hip_bfloat16* __restrict__ Y, int M, int N, int K)
{
  __shared__ __hip_bfloat16 As[128 * 32];
  __shared__ __hip_bfloat16 Bs[128 * 32];
  const int tid  = threadIdx.x;
  const int lane = tid & 63;
  const int wave = tid >> 6;
  const int bm = blockIdx.x * 128;
  const int bn = blockIdx.y * 128;
  const int wr = (wave >> 1) * 64;
  const int wc = (wave & 1) * 64;
  const int srow  = tid >> 2;
  const int skoff = (tid & 3) * 8;

  f32x16 acc[2][2] = {};
  const float* gA0 = X + (size_t)(bm + srow) * K + skoff;
  const float* gA1 = X + (size_t)(bm + 64 + srow) * K + skoff;
  const __hip_bfloat16* gB0 = W + (size_t)(bn + srow) * K + skoff;
  const __hip_bfloat16* gB1 = W + (size_t)(bn + 64 + srow) * K + skoff;

  const int arow  = lane & 31;
  const int akoff = (lane >> 5) * 8;

  for (int k0 = 0; k0 < K; k0 += 32) {
    const Ld8f va0 = ld8(gA0 + k0);       // fp32 A -> regs (issued early)
    const Ld8f va1 = ld8(gA1 + k0);
    __syncthreads();                       // prev iter LDS reads done
    gl_lds16(gB0 + k0, &Bs[tid * 8]);      // B bf16 -> LDS (dest byte = tid*16)
    gl_lds16(gB1 + k0, &Bs[2048 + tid * 8]);
    st8(&As[srow * 32 + skoff],        va0);   // cvt + ds_write_b128
    st8(&As[(64 + srow) * 32 + skoff], va1);
    __syncthreads();                       // drains gl_lds (vmcnt) + ds_writes

    frag8 a[2][2], b[2][2];
#pragma unroll
    for (int i = 0; i < 2; i++)
#pragma unroll
      for (int h = 0; h < 2; h++) {
        a[i][h] = *(const frag8*)&As[(wr + i * 32 + arow) * 32 + h * 16 + akoff];
        b[i][h] = *(const frag8*)&Bs[(wc + i * 32 + arow) * 32 + h * 16 + akoff];
      }
#pragma unroll
    for (int h = 0; h < 2; h++)
#pragma unroll
      for (int i = 0; i < 2; i++)
#pragma unroll
        for (int j = 0; j < 2; j++)
          acc[i][j] = __builtin_amdgcn_mfma_f32_32x32x16_bf16(a[i][h], b[j][h], acc[i][j], 0, 0, 0);
  }

  // C/D layout (32x32): col=lane&31, row=(r&3)+8*(r>>2)+4*(lane>>5)  [m74/m101]
#pragma unroll
  for (int i = 0; i < 2; i++)
#pragma unroll
    for (int j = 0; j < 2; j++) {
      const int col = bn + wc + j * 32 + (lane & 31);
      const float bv = bias[col];
#pragma unroll
      for (int r = 0; r < 16; r++) {
        const int row = bm + wr + i * 32 + (r & 3) + 8 * (r >> 2) + 4 * (lane >> 5);
        store_out(Y, (size_t)row * N + col, acc[i][j][r] + bv);
      }
    }
}

// ------- gemm2: BK=64 double-buffered, bf16 both sides via gl_lds (round-7 kernel) ----
template <typename TY>
__global__ __launch_bounds__(256, 2)
void gemm_db(const __hip_bfloat16* __restrict__ X,
             const __hip_bfloat16* __restrict__ W,
             const float* __restrict__ bias,
             TY* __restrict__ Y, int M, int N, int K)
{
  __shared__ __hip_bfloat16 As[2][2][128 * 32];
  __shared__ __hip_bfloat16 Bs[2][2][128 * 32];
  const int tid  = threadIdx.x;
  const int lane = tid & 63;
  const int wave = tid >> 6;
  const int bm = blockIdx.x * 128;
  const int bn = blockIdx.y * 128;
  const int wr = (wave >> 1) * 64;
  const int wc = (wave & 1) * 64;
  const int srow  = tid >> 2;
  const int skoff = (tid & 3) * 8;

  const __hip_bfloat16* gA0 = X + (size_t)(bm + srow) * K + skoff;
  const __hip_bfloat16* gA1 = X + (size_t)(bm + 64 + srow) * K + skoff;
  const __hip_bfloat16* gB0 = W + (size_t)(bn + srow) * K + skoff;
  const __hip_bfloat16* gB1 = W + (size_t)(bn + 64 + srow) * K + skoff;

  f32x16 acc[2][2] = {};
  const int arow  = lane & 31;
  const int akoff = (lane >> 5) * 8;

#define STAGE(k0, buf)                                        \
  do {                                                        \
    gl_lds16(gA0 + (k0),      &As[buf][0][tid * 8]);          \
    gl_lds16(gA1 + (k0),      &As[buf][0][2048 + tid * 8]);   \
    gl_lds16(gA0 + (k0) + 32, &As[buf][1][tid * 8]);          \
    gl_lds16(gA1 + (k0) + 32, &As[buf][1][2048 + tid * 8]);   \
    gl_lds16(gB0 + (k0),      &Bs[buf][0][tid * 8]);          \
    gl_lds16(gB1 + (k0),      &Bs[buf][0][2048 + tid * 8]);   \
    gl_lds16(gB0 + (k0) + 32, &Bs[buf][1][tid * 8]);          \
    gl_lds16(gB1 + (k0) + 32, &Bs[buf][1][2048 + tid * 8]);   \
  } while (0)

  STAGE(0, 0);
  __syncthreads();
  const int iters = K / 64;
  for (int it = 0; it < iters; ++it) {
    const int cur = it & 1;
    if (it + 1 < iters) STAGE((it + 1) * 64, cur ^ 1);

#pragma unroll
    for (int p = 0; p < 2; ++p)
#pragma unroll
      for (int h = 0; h < 2; ++h) {
        const frag8 a0 = *(const frag8*)&As[cur][p][(wr + arow) * 32 + h * 16 + akoff];
        const frag8 a1 = *(const frag8*)&As[cur][p][(wr + 32 + arow) * 32 + h * 16 + akoff];
        const frag8 b0 = *(const frag8*)&Bs[cur][p][(wc + arow) * 32 + h * 16 + akoff];
        const frag8 b1 = *(const frag8*)&Bs[cur][p][(wc + 32 + arow) * 32 + h * 16 + akoff];
        acc[0][0] = __builtin_amdgcn_mfma_f32_32x32x16_bf16(a0, b0, acc[0][0], 0, 0, 0);
        acc[0][1] = __builtin_amdgcn_mfma_f32_32x32x16_bf16(a0, b1, acc[0][1], 0, 0, 0);
        acc[1][0] = __builtin_amdgcn_mfma_f32_32x32x16_bf16(a1, b0, acc[1][0], 0, 0, 0);
        acc[1][1] = __builtin_amdgcn_mfma_f32_32x32x16_bf16(a1, b1, acc[1][1], 0, 0, 0);
      }
    __syncthreads();
  }
#undef STAGE

#pragma unroll
  for (int i = 0; i < 2; i++)
#pragma unroll
    for (int j = 0; j < 2; j++) {
      const int col = bn + wc + j * 32 + (lane & 31);
      const float bv = bias[col];
#pragma unroll
      for (int r = 0; r < 16; r++) {
        const int row = bm + wr + i * 32 + (r & 3) + 8 * (r >> 2) + 4 * (lane >> 5);
        store_out(Y, (size_t)row * N + col, acc[i][j][r] + bv);
      }
    }
}

// ------- mid v5: exact v2 structure (erff, 53us proven) + bf16 Wo/Wm loads -------
__global__ __launch_bounds__(256)
void mid_fused_v5(const float* __restrict__ x,
                  const float* __restrict__ dw_w, const float* __restrict__ dw_b,
                  const float* __restrict__ ln_g, const float* __restrict__ ln_b,
                  const __hip_bfloat16* __restrict__ Wob, const float* __restrict__ bo,
                  const __hip_bfloat16* __restrict__ Wmb, const float* __restrict__ bmb,
                  const __hip_bfloat16* __restrict__ xp,
                  __hip_bfloat16* __restrict__ smp)
{
  const int b    = blockIdx.x;                 // 2048 blocks
  const int bs   = (b & 7) * 256 + (b >> 3);   // XCD-contiguous row spans
  const int wid  = threadIdx.x >> 6;
  const int lane = threadIdx.x & 63;
  const int row  = bs * 4 + wid;
  const int l    = row & (L_DIM - 1);
  const int n    = row >> 11;

  const float* xr = x + (size_t)row * C_DIM;

  float4 v[4];
#pragma unroll
  for (int j = 0; j < 4; j++) {
    const int c4 = j * 256 + lane * 4;
    const float4 x0 = *(const float4*)(xr + c4);
    float4 xm = make_float4(0.f, 0.f, 0.f, 0.f);
    float4 xq = make_float4(0.f, 0.f, 0.f, 0.f);
    if (l > 0)         xm = *(const float4*)(xr + c4 - C_DIM);
    if (l < L_DIM - 1) xq = *(const float4*)(xr + c4 + C_DIM);
    const float4 w0 = *(const float4*)(dw_w + (size_t)c4 * 3);
    const float4 w1 = *(const float4*)(dw_w + (size_t)c4 * 3 + 4);
    const float4 w2 = *(const float4*)(dw_w + (size_t)c4 * 3 + 8);
    const float4 bb = *(const float4*)(dw_b + c4);
    v[j].x = xm.x * w0.x + x0.x * w0.y + xq.x * w0.z + bb.x;
    v[j].y = xm.y * w0.w + x0.y * w1.x + xq.y * w1.y + bb.y;
    v[j].z = xm.z * w1.z + x0.z * w1.w + xq.z * w2.x + bb.z;
    v[j].w = xm.w * w2.y + x0.w * w2.z + xq.w * w2.w + bb.w;
  }

  float s1 = 0.f, s2 = 0.f;
#pragma unroll
  for (int j = 0; j < 4; j++) {
    s1 += v[j].x + v[j].y + v[j].z + v[j].w;
    s2 += v[j].x * v[j].x + v[j].y * v[j].y + v[j].z * v[j].z + v[j].w * v[j].w;
  }
#pragma unroll
  for (int m = 1; m < 64; m <<= 1) { s1 += __shfl_xor(s1, m); s2 += __shfl_xor(s2, m); }
  const float mu   = s1 * (1.f / C_DIM);
  const float rstd = rsqrtf(s2 * (1.f / C_DIM) - mu * mu + 1e-5f);

  float4 g[4];
#pragma unroll
  for (int j = 0; j < 4; j++) {
    const int c4 = j * 256 + lane * 4;
    const float4 gg = *(const float4*)(ln_g + c4);
    const float4 bb = *(const float4*)(ln_b + c4);
    float t;
    t = (v[j].x - mu) * rstd * gg.x + bb.x; g[j].x = 0.5f * t * (1.f + erff(t * 0.70710678f));
    t = (v[j].y - mu) * rstd * gg.y + bb.y; g[j].y = 0.5f * t * (1.f + erff(t * 0.70710678f));
    t = (v[j].z - mu) * rstd * gg.z + bb.z; g[j].z = 0.5f * t * (1.f + erff(t * 0.70710678f));
    t = (v[j].w - mu) * rstd * gg.w + bb.w; g[j].w = 0.5f * t * (1.f + erff(t * 0.70710678f));
  }

  float po[7] = {0,0,0,0,0,0,0}, pm[7] = {0,0,0,0,0,0,0};
#pragma unroll
  for (int k = 0; k < 7; k++) {
#pragma unroll
    for (int j = 0; j < 4; j++) {
      const int c4 = j * 256 + lane * 4;
      const float4 wo = ldbf4(Wob + (size_t)k * C_DIM + c4);
      const float4 wm = ldbf4(Wmb + (size_t)k * C_DIM + c4);
      po[k] += g[j].x * wo.x + g[j].y * wo.y + g[j].z * wo.z + g[j].w * wo.w;
      pm[k] += g[j].x * wm.x + g[j].y * wm.y + g[j].z * wm.z + g[j].w * wm.w;
    }
  }
#pragma unroll
  for (int k = 0; k < 7; k++)
#pragma unroll
    for (int m = 1; m < 64; m <<= 1) {
      po[k] += __shfl_xor(po[k], m);
      pm[k] += __shfl_xor(pm[k], m);
    }

  float lg[7], mx = -1e30f;
#pragma unroll
  for (int k = 0; k < 7; k++) { lg[k] = pm[k] + bmb[k]; mx = fmaxf(mx, lg[k]); }
  float se = 0.f, e[7];
#pragma unroll
  for (int k = 0; k < 7; k++) { e[k] = __expf(lg[k] - mx); se += e[k]; }
  const float inv = 1.f / se;

  float wf[7], wcl[7]; int pf[7], pc[7];
#pragma unroll
  for (int k = 0; k < 7; k++) {
    const float msk = e[k] * inv;
    const float off = (po[k] + bo[k]) * 2.0f;
    const float ap  = (float)l + (float)(k - 3) + off;
    const float apc = fminf(fmaxf(ap, 0.f), (float)(L_DIM - 1));
    int f = (int)apc;
    int c = f + 1; if (c > L_DIM - 1) c = L_DIM - 1;
    const float w1  = apc - (float)f;
    const float val = (ap < 0.f || ap > (float)(L_DIM - 1)) ? 0.f : 1.f;
    wf[k]  = (1.f - w1) * val * msk;
    wcl[k] = w1 * val * msk;
    pf[k] = f; pc[k] = c;
  }

  const __hip_bfloat16* xpn = xp + ((size_t)n * L_DIM) * C_DIM;
  __hip_bfloat16* so = smp + (size_t)row * C_DIM;
#pragma unroll
  for (int j = 0; j < 4; j++) {
    const int c4 = j * 256 + lane * 4;
    float4 a = make_float4(0.f, 0.f, 0.f, 0.f);
#pragma unroll
    for (int k = 0; k < 7; k++) {
      const float4 vf = ldbf4(xpn + (size_t)pf[k] * C_DIM + c4);
      const float4 vc = ldbf4(xpn + (size_t)pc[k] * C_DIM + c4);
      a.x += wf[k] * vf.x + wcl[k] * vc.x;
      a.y += wf[k] * vf.y + wcl[k] * vc.y;
      a.z += wf[k] * vf.z + wcl[k] * vc.z;
      a.w += wf[k] * vf.w + wcl[k] * vc.w;
    }
    stbf4(so + c4, a);
  }
}

// ---------------- host ----------------
extern "C" void kernel_launch(void* const* d_in, const int* in_sizes, int n_in,
                              void* d_out, int out_size, void* d_ws, size_t ws_size,
                              hipStream_t stream)
{
  const float* x    = (const float*)d_in[0];
  const float* Wi   = (const float*)d_in[1];
  const float* bi   = (const float*)d_in[2];
  const float* dw_w = (const float*)d_in[3];
  const float* dw_b = (const float*)d_in[4];
  const float* ln_g = (const float*)d_in[5];
  const float* ln_b = (const float*)d_in[6];
  const float* Wo   = (const float*)d_in[7];
  const float* bo   = (const float*)d_in[8];
  const float* Wm   = (const float*)d_in[9];
  const float* bm   = (const float*)d_in[10];
  const float* Wout = (const float*)d_in[11];
  const float* bout = (const float*)d_in[12];
  float* out = (float*)d_out;

  const size_t XE = (size_t)M_DIM * C_DIM;   // 8,388,608
  const size_t WE = (size_t)C_DIM * C_DIM;   // 1,048,576
  char* wsb = (char*)d_ws;
  __hip_bfloat16* xp    = (__hip_bfloat16*)wsb;                          // 16 MB
  __hip_bfloat16* smp   = (__hip_bfloat16*)(wsb + XE * 2);               // 16 MB
  __hip_bfloat16* Wib   = (__hip_bfloat16*)(wsb + XE * 4);               // 2 MB
  __hip_bfloat16* Woutb = (__hip_bfloat16*)(wsb + XE * 4 + WE * 2);      // 2 MB
  __hip_bfloat16* Wob   = (__hip_bfloat16*)(wsb + XE * 4 + WE * 4);      // 14 KB
  __hip_bfloat16* Wmb   = (__hip_bfloat16*)(wsb + XE * 4 + WE * 4 + 14336);

  dim3 gg(M_DIM / 128, C_DIM / 128);   // 64 x 8

  cvt_weights<<<1032, 256, 0, stream>>>(Wi, Wout, Wo, Wm, Wib, Woutb, Wob, Wmb);
  gemm_hyb<<<gg, 256, 0, stream>>>(x, Wib, bi, xp, M_DIM, C_DIM, C_DIM);
  mid_fused_v5<<<M_DIM / 4, 256, 0, stream>>>(x, dw_w, dw_b, ln_g, ln_b, Wob, bo, Wmb, bm, xp, smp);
  gemm_db<float><<<gg, 256, 0, stream>>>(smp, Woutb, bout, out, M_DIM, C_DIM, C_DIM);
}

// Round 9
// 211.515 us; speedup vs baseline: 1.1321x; 1.1321x over previous
//
#include <hip/hip_runtime.h>
#include <hip/hip_bf16.h>
#include <cstdint>

#define C_DIM 1024
#define L_DIM 2048
#define N_DIM 4
#define M_DIM (N_DIM * L_DIM)   // 8192

typedef __attribute__((ext_vector_type(8))) short frag8;    // 8 bf16 = 4 VGPRs
typedef __attribute__((ext_vector_type(16))) float f32x16;

// ---------------- helpers ----------------
__device__ __forceinline__ void gl_lds16(const void* g, void* l) {
  __builtin_amdgcn_global_load_lds((const __attribute__((address_space(1))) void*)g,
                                   (__attribute__((address_space(3))) void*)l,
                                   16, 0, 0);
}
__device__ __forceinline__ void store_out(float* Y, size_t idx, float v) { Y[idx] = v; }
__device__ __forceinline__ void store_out(__hip_bfloat16* Y, size_t idx, float v) {
  Y[idx] = __float2bfloat16(v);
}
__device__ __forceinline__ float4 ldbf4(const __hip_bfloat16* p) {
  union { short4 s; __hip_bfloat16 h[4]; } u; u.s = *(const short4*)p;
  return make_float4((float)u.h[0], (float)u.h[1], (float)u.h[2], (float)u.h[3]);
}
__device__ __forceinline__ void stbf4(__hip_bfloat16* p, float4 v) {
  union { short4 s; __hip_bfloat16 h[4]; } u;
  u.h[0] = __float2bfloat16(v.x); u.h[1] = __float2bfloat16(v.y);
  u.h[2] = __float2bfloat16(v.z); u.h[3] = __float2bfloat16(v.w);
  *(short4*)p = u.s;
}
struct Ld8f { float4 a, b; };
__device__ __forceinline__ Ld8f ld8(const float* p) {
  return { *(const float4*)p, *(const float4*)(p + 4) };
}
__device__ __forceinline__ void st8(__hip_bfloat16* l, const Ld8f& v) {
  union { __hip_bfloat16 h[8]; int4 q; } u;
  u.h[0] = __float2bfloat16(v.a.x); u.h[1] = __float2bfloat16(v.a.y);
  u.h[2] = __float2bfloat16(v.a.z); u.h[3] = __float2bfloat16(v.a.w);
  u.h[4] = __float2bfloat16(v.b.x); u.h[5] = __float2bfloat16(v.b.y);
  u.h[6] = __float2bfloat16(v.b.z); u.h[7] = __float2bfloat16(v.b.w);
  *(int4*)l = u.q;
}

// ---- weight conversion: Wi, Wout -> bf16 (1024 blocks) ----
__global__ __launch_bounds__(256)
void cvt_weights(const float* __restrict__ Wi, const float* __restrict__ Wout,
                 __hip_bfloat16* __restrict__ Wib, __hip_bfloat16* __restrict__ Woutb)
{
  const int b = blockIdx.x;
  const float* src = (b < 512) ? Wi : Wout;
  __hip_bfloat16* dst = (b < 512) ? Wib : Woutb;
  const int i = (b & 511) * 256 + threadIdx.x;   // < 131072 always (512*256)
  st8(dst + (size_t)i * 8, ld8(src + (size_t)i * 8));
}

// =====================================================================
// GEMM: Y[M,N] = X[M,K] @ W[N,K]^T + bias.  128x64 tile, BK=32, dbuf,
// 32x32x16 MFMA, XOR bank swizzle: physical chunk = logical ^ ((row>>1)&3).
// 1024 blocks (4/CU), 256 threads, wave w owns rows [w*32, w*32+32), all 64 cols.
// =====================================================================

// gemm1: X fp32 (register-staged A, inline cvt), W bf16 (gl_lds B).
__global__ __launch_bounds__(256, 4)
void gemm_fb(const float* __restrict__ X, const __hip_bfloat16* __restrict__ W,
             const float* __restrict__ bias, __hip_bfloat16* __restrict__ Y,
             int M, int N, int K)
{
  __shared__ __hip_bfloat16 As[2][128 * 32];   // 8 KB x2
  __shared__ __hip_bfloat16 Bs[2][64 * 32];    // 4 KB x2
  const int tid  = threadIdx.x;
  const int lane = tid & 63;
  const int w    = tid >> 6;
  const int bm = blockIdx.x * 128;
  const int bn = blockIdx.y * 64;

  // A staging (register path): thread t handles logical chunks of rows ar0, ar0+64
  const int ar0 = tid >> 2;                       // 0..63
  const int ac  = tid & 3;                        // logical k-chunk
  const int apc = ac ^ ((ar0 >> 1) & 3);          // physical chunk (same for row+64)
  // B staging (gl_lds path): thread t fills physical chunk t -> fetch logical:
  const int br  = tid >> 2;
  const int blc = (tid & 3) ^ ((br >> 1) & 3);    // logical chunk to fetch

  const float* gA0 = X + (size_t)(bm + ar0) * K + ac * 8;
  const float* gA1 = X + (size_t)(bm + 64 + ar0) * K + ac * 8;
  const __hip_bfloat16* gB = W + (size_t)(bn + br) * K + blc * 8;

  f32x16 acc[2] = {};
  const int arow = lane & 31;
  const int sel  = lane >> 5;
  const int s    = (arow >> 1) & 3;     // swizzle key (same for row, row+32, row+64)

  { // prologue: tile 0
    const Ld8f va0 = ld8(gA0), va1 = ld8(gA1);
    gl_lds16(gB, &Bs[0][tid * 8]);
    st8(&As[0][ar0 * 32 + apc * 8],        va0);
    st8(&As[0][(64 + ar0) * 32 + apc * 8], va1);
  }
  __syncthreads();

  const int iters = K / 32;
  for (int it = 0; it < iters; ++it) {
    const int cur = it & 1, nxt = cur ^ 1;
    Ld8f va0, va1;
    const bool pf = (it + 1 < iters);
    if (pf) {
      va0 = ld8(gA0 + (it + 1) * 32);            // in flight across MFMA
      va1 = ld8(gA1 + (it + 1) * 32);
      gl_lds16(gB + (it + 1) * 32, &Bs[nxt][tid * 8]);
    }

    frag8 a[2], bf[2][2];
#pragma unroll
    for (int h = 0; h < 2; ++h) {
      const int pc = ((h * 2 + sel) ^ s) * 8;
      a[h]     = *(const frag8*)&As[cur][(w * 32 + arow) * 32 + pc];
      bf[0][h] = *(const frag8*)&Bs[cur][arow * 32 + pc];
      bf[1][h] = *(const frag8*)&Bs[cur][(32 + arow) * 32 + pc];
    }
#pragma unroll
    for (int h = 0; h < 2; ++h) {
      acc[0] = __builtin_amdgcn_mfma_f32_32x32x16_bf16(a[h], bf[0][h], acc[0], 0, 0, 0);
      acc[1] = __builtin_amdgcn_mfma_f32_32x32x16_bf16(a[h], bf[1][h], acc[1], 0, 0, 0);
    }
    if (pf) {
      st8(&As[nxt][ar0 * 32 + apc * 8],        va0);   // waits va (overlapped MFMA)
      st8(&As[nxt][(64 + ar0) * 32 + apc * 8], va1);
    }
    __syncthreads();
  }

  // C/D layout (32x32): col=lane&31, row=(r&3)+8*(r>>2)+4*(lane>>5)  [m74/m101]
#pragma unroll
  for (int j = 0; j < 2; ++j) {
    const int col = bn + j * 32 + (lane & 31);
    const float bv = bias[col];
#pragma unroll
    for (int r = 0; r < 16; ++r) {
      const int row = bm + w * 32 + (r & 3) + 8 * (r >> 2) + 4 * sel;
      store_out(Y, (size_t)row * N + col, acc[j][r] + bv);
    }
  }
}

// gemm2: X bf16 and W bf16 both via gl_lds.
template <typename TY>
__global__ __launch_bounds__(256, 4)
void gemm_bb(const __hip_bfloat16* __restrict__ X, const __hip_bfloat16* __restrict__ W,
             const float* __restrict__ bias, TY* __restrict__ Y,
             int M, int N, int K)
{
  __shared__ __hip_bfloat16 As[2][128 * 32];
  __shared__ __hip_bfloat16 Bs[2][64 * 32];
  const int tid  = threadIdx.x;
  const int lane = tid & 63;
  const int w    = tid >> 6;
  const int bm = blockIdx.x * 128;
  const int bn = blockIdx.y * 64;

  // A: physical chunks tid and tid+256; fetch their logical chunk.
  const int ar0 = tid >> 2;
  const int alc = (tid & 3) ^ ((ar0 >> 1) & 3);   // same swizzle key for row+64
  const int br  = tid >> 2;
  const int blc = (tid & 3) ^ ((br >> 1) & 3);

  const __hip_bfloat16* gA0 = X + (size_t)(bm + ar0) * K + alc * 8;
  const __hip_bfloat16* gA1 = X + (size_t)(bm + 64 + ar0) * K + alc * 8;
  const __hip_bfloat16* gB  = W + (size_t)(bn + br) * K + blc * 8;

  f32x16 acc[2] = {};
  const int arow = lane & 31;
  const int sel  = lane >> 5;
  const int s    = (arow >> 1) & 3;

#define STAGE_BB(k0, buf)                              \
  do {                                                 \
    gl_lds16(gA0 + (k0), &As[buf][tid * 8]);           \
    gl_lds16(gA1 + (k0), &As[buf][2048 + tid * 8]);    \
    gl_lds16(gB  + (k0), &Bs[buf][tid * 8]);           \
  } while (0)

  STAGE_BB(0, 0);
  __syncthreads();

  const int iters = K / 32;
  for (int it = 0; it < iters; ++it) {
    const int cur = it & 1, nxt = cur ^ 1;
    if (it + 1 < iters) STAGE_BB((it + 1) * 32, nxt);

    frag8 a[2], bf[2][2];
#pragma unroll
    for (int h = 0; h < 2; ++h) {
      const int pc = ((h * 2 + sel) ^ s) * 8;
      a[h]     = *(const frag8*)&As[cur][(w * 32 + arow) * 32 + pc];
      bf[0][h] = *(const frag8*)&Bs[cur][arow * 32 + pc];
      bf[1][h] = *(const frag8*)&Bs[cur][(32 + arow) * 32 + pc];
    }
#pragma unroll
    for (int h = 0; h < 2; ++h) {
      acc[0] = __builtin_amdgcn_mfma_f32_32x32x16_bf16(a[h], bf[0][h], acc[0], 0, 0, 0);
      acc[1] = __builtin_amdgcn_mfma_f32_32x32x16_bf16(a[h], bf[1][h], acc[1], 0, 0, 0);
    }
    __syncthreads();
  }
#undef STAGE_BB

#pragma unroll
  for (int j = 0; j < 2; ++j) {
    const int col = bn + j * 32 + (lane & 31);
    const float bv = bias[col];
#pragma unroll
    for (int r = 0; r < 16; ++r) {
      const int row = bm + w * 32 + (r & 3) + 8 * (r >> 2) + 4 * sel;
      store_out(Y, (size_t)row * N + col, acc[j][r] + bv);
    }
  }
}

// ------- mid: exact v2 structure (53 us measured) — one wave per row -------
__global__ __launch_bounds__(256)
void mid_fused_v2(const float* __restrict__ x,
                  const float* __restrict__ dw_w, const float* __restrict__ dw_b,
                  const float* __restrict__ ln_g, const float* __restrict__ ln_b,
                  const float* __restrict__ Wo,   const float* __restrict__ bo,
                  const float* __restrict__ Wm,   const float* __restrict__ bmb,
                  const __hip_bfloat16* __restrict__ xp,
                  __hip_bfloat16* __restrict__ smp)
{
  const int b    = blockIdx.x;                 // 2048 blocks
  const int bs   = (b & 7) * 256 + (b >> 3);   // XCD-contiguous row spans
  const int wid  = threadIdx.x >> 6;
  const int lane = threadIdx.x & 63;
  const int row  = bs * 4 + wid;
  const int l    = row & (L_DIM - 1);
  const int n    = row >> 11;

  const float* xr = x + (size_t)row * C_DIM;

  float4 v[4];
#pragma unroll
  for (int j = 0; j < 4; j++) {
    const int c4 = j * 256 + lane * 4;
    const float4 x0 = *(const float4*)(xr + c4);
    float4 xm = make_float4(0.f, 0.f, 0.f, 0.f);
    float4 xq = make_float4(0.f, 0.f, 0.f, 0.f);
    if (l > 0)         xm = *(const float4*)(xr + c4 - C_DIM);
    if (l < L_DIM - 1) xq = *(const float4*)(xr + c4 + C_DIM);
    const float4 w0 = *(const float4*)(dw_w + (size_t)c4 * 3);
    const float4 w1 = *(const float4*)(dw_w + (size_t)c4 * 3 + 4);
    const float4 w2 = *(const float4*)(dw_w + (size_t)c4 * 3 + 8);
    const float4 bb = *(const float4*)(dw_b + c4);
    v[j].x = xm.x * w0.x + x0.x * w0.y + xq.x * w0.z + bb.x;
    v[j].y = xm.y * w0.w + x0.y * w1.x + xq.y * w1.y + bb.y;
    v[j].z = xm.z * w1.z + x0.z * w1.w + xq.z * w2.x + bb.z;
    v[j].w = xm.w * w2.y + x0.w * w2.z + xq.w * w2.w + bb.w;
  }

  float s1 = 0.f, s2 = 0.f;
#pragma unroll
  for (int j = 0; j < 4; j++) {
    s1 += v[j].x + v[j].y + v[j].z + v[j].w;
    s2 += v[j].x * v[j].x + v[j].y * v[j].y + v[j].z * v[j].z + v[j].w * v[j].w;
  }
#pragma unroll
  for (int m = 1; m < 64; m <<= 1) { s1 += __shfl_xor(s1, m); s2 += __shfl_xor(s2, m); }
  const float mu   = s1 * (1.f / C_DIM);
  const float rstd = rsqrtf(s2 * (1.f / C_DIM) - mu * mu + 1e-5f);

  float4 g[4];
#pragma unroll
  for (int j = 0; j < 4; j++) {
    const int c4 = j * 256 + lane * 4;
    const float4 gg = *(const float4*)(ln_g + c4);
    const float4 bb = *(const float4*)(ln_b + c4);
    float t;
    t = (v[j].x - mu) * rstd * gg.x + bb.x; g[j].x = 0.5f * t * (1.f + erff(t * 0.70710678f));
    t = (v[j].y - mu) * rstd * gg.y + bb.y; g[j].y = 0.5f * t * (1.f + erff(t * 0.70710678f));
    t = (v[j].z - mu) * rstd * gg.z + bb.z; g[j].z = 0.5f * t * (1.f + erff(t * 0.70710678f));
    t = (v[j].w - mu) * rstd * gg.w + bb.w; g[j].w = 0.5f * t * (1.f + erff(t * 0.70710678f));
  }

  float po[7] = {0,0,0,0,0,0,0}, pm[7] = {0,0,0,0,0,0,0};
#pragma unroll
  for (int k = 0; k < 7; k++) {
#pragma unroll
    for (int j = 0; j < 4; j++) {
      const int c4 = j * 256 + lane * 4;
      const float4 wo = *(const float4*)(Wo + (size_t)k * C_DIM + c4);
      const float4 wm = *(const float4*)(Wm + (size_t)k * C_DIM + c4);
      po[k] += g[j].x * wo.x + g[j].y * wo.y + g[j].z * wo.z + g[j].w * wo.w;
      pm[k] += g[j].x * wm.x + g[j].y * wm.y + g[j].z * wm.z + g[j].w * wm.w;
    }
  }
#pragma unroll
  for (int k = 0; k < 7; k++)
#pragma unroll
    for (int m = 1; m < 64; m <<= 1) {
      po[k] += __shfl_xor(po[k], m);
      pm[k] += __shfl_xor(pm[k], m);
    }

  float lg[7], mx = -1e30f;
#pragma unroll
  for (int k = 0; k < 7; k++) { lg[k] = pm[k] + bmb[k]; mx = fmaxf(mx, lg[k]); }
  float se = 0.f, e[7];
#pragma unroll
  for (int k = 0; k < 7; k++) { e[k] = __expf(lg[k] - mx); se += e[k]; }
  const float inv = 1.f / se;

  float wf[7], wcl[7]; int pf[7], pc[7];
#pragma unroll
  for (int k = 0; k < 7; k++) {
    const float msk = e[k] * inv;
    const float off = (po[k] + bo[k]) * 2.0f;
    const float ap  = (float)l + (float)(k - 3) + off;
    const float apc = fminf(fmaxf(ap, 0.f), (float)(L_DIM - 1));
    int f = (int)apc;
    int c = f + 1; if (c > L_DIM - 1) c = L_DIM - 1;
    const float w1  = apc - (float)f;
    const float val = (ap < 0.f || ap > (float)(L_DIM - 1)) ? 0.f : 1.f;
    wf[k]  = (1.f - w1) * val * msk;
    wcl[k] = w1 * val * msk;
    pf[k] = f; pc[k] = c;
  }

  const __hip_bfloat16* xpn = xp + ((size_t)n * L_DIM) * C_DIM;
  __hip_bfloat16* so = smp + (size_t)row * C_DIM;
#pragma unroll
  for (int j = 0; j < 4; j++) {
    const int c4 = j * 256 + lane * 4;
    float4 a = make_float4(0.f, 0.f, 0.f, 0.f);
#pragma unroll
    for (int k = 0; k < 7; k++) {
      const float4 vf = ldbf4(xpn + (size_t)pf[k] * C_DIM + c4);
      const float4 vc = ldbf4(xpn + (size_t)pc[k] * C_DIM + c4);
      a.x += wf[k] * vf.x + wcl[k] * vc.x;
      a.y += wf[k] * vf.y + wcl[k] * vc.y;
      a.z += wf[k] * vf.z + wcl[k] * vc.z;
      a.w += wf[k] * vf.w + wcl[k] * vc.w;
    }
    stbf4(so + c4, a);
  }
}

// ---------------- host ----------------
extern "C" void kernel_launch(void* const* d_in, const int* in_sizes, int n_in,
                              void* d_out, int out_size, void* d_ws, size_t ws_size,
                              hipStream_t stream)
{
  const float* x    = (const float*)d_in[0];
  const float* Wi   = (const float*)d_in[1];
  const float* bi   = (const float*)d_in[2];
  const float* dw_w = (const float*)d_in[3];
  const float* dw_b = (const float*)d_in[4];
  const float* ln_g = (const float*)d_in[5];
  const float* ln_b = (const float*)d_in[6];
  const float* Wo   = (const float*)d_in[7];
  const float* bo   = (const float*)d_in[8];
  const float* Wm   = (const float*)d_in[9];
  const float* bm   = (const float*)d_in[10];
  const float* Wout = (const float*)d_in[11];
  const float* bout = (const float*)d_in[12];
  float* out = (float*)d_out;

  const size_t XE = (size_t)M_DIM * C_DIM;   // 8,388,608
  const size_t WE = (size_t)C_DIM * C_DIM;   // 1,048,576
  char* wsb = (char*)d_ws;
  __hip_bfloat16* xp    = (__hip_bfloat16*)wsb;                     // 16 MB
  __hip_bfloat16* smp   = (__hip_bfloat16*)(wsb + XE * 2);          // 16 MB
  __hip_bfloat16* Wib   = (__hip_bfloat16*)(wsb + XE * 4);          // 2 MB
  __hip_bfloat16* Woutb = (__hip_bfloat16*)(wsb + XE * 4 + WE * 2); // 2 MB

  dim3 gg(M_DIM / 128, C_DIM / 64);   // 64 x 16 = 1024 blocks

  cvt_weights<<<1024, 256, 0, stream>>>(Wi, Wout, Wib, Woutb);
  gemm_fb<<<gg, 256, 0, stream>>>(x, Wib, bi, xp, M_DIM, C_DIM, C_DIM);
  mid_fused_v2<<<M_DIM / 4, 256, 0, stream>>>(x, dw_w, dw_b, ln_g, ln_b, Wo, bo, Wm, bm, xp, smp);
  gemm_bb<float><<<gg, 256, 0, stream>>>(smp, Woutb, bout, out, M_DIM, C_DIM, C_DIM);
}